// Round 1
// baseline (197.309 us; speedup 1.0000x reference)
//
#include <hip/hip_runtime.h>

static constexpr int Hh  = 1024;
static constexpr int Wd  = 1024;
static constexpr int NCH = 16;

// ---------------- Kernel 1: global max |xc| ----------------
__global__ __launch_bounds__(256) void k_maxabs(const float* __restrict__ x,
                                                unsigned int* __restrict__ omax,
                                                int n4) {
    float m = 0.0f;
    int stride = gridDim.x * blockDim.x;
    for (int i = blockIdx.x * blockDim.x + threadIdx.x; i < n4; i += stride) {
        float4 v = reinterpret_cast<const float4*>(x)[i];
        int w0 = (i * 4) & (Wd - 1);
        float left = (w0 == 0) ? 0.0f : x[i * 4 - 1];
        float d0 = v.x - left;
        float d1 = v.y - v.x;
        float d2 = v.z - v.y;
        float d3 = v.w - v.z;
        m = fmaxf(m, fmaxf(fmaxf(fabsf(d0), fabsf(d1)), fmaxf(fabsf(d2), fabsf(d3))));
    }
#pragma unroll
    for (int off = 32; off >= 1; off >>= 1)
        m = fmaxf(m, __shfl_xor(m, off));
    __shared__ float smax[4];
    int lane = threadIdx.x & 63;
    int wv   = threadIdx.x >> 6;
    if (lane == 0) smax[wv] = m;
    __syncthreads();
    if (threadIdx.x == 0) {
        float mm = fmaxf(fmaxf(smax[0], smax[1]), fmaxf(smax[2], smax[3]));
        atomicMax(omax, __float_as_uint(mm));
    }
}

// ---------------- Kernel 2: per-8x8-block LS fit + select ----------------
__device__ __forceinline__ float quantv(float v, float inv_lsb, float lsb) {
    return rintf(v * inv_lsb) * lsb;   // lsb is a power of two: exact
}

__global__ __launch_bounds__(256) void k_blocks(const float* __restrict__ x,
                                                const unsigned int* __restrict__ pmax,
                                                float* __restrict__ out) {
    const int blk = blockIdx.x;        // 0..16383, wb fast for L2 locality
    const int wb  = blk & 127;
    const int hb  = blk >> 7;
    const int w0  = wb * 8;
    const int h0  = hb * 8;
    const int tid = threadIdx.x;

    // raw[row][c] holds x[n, h0+i, w0-4+c], row = n*8+i, c = 0..11
    __shared__ float raw[128][12];

    for (int v = tid; v < 384; v += 256) {
        int row = v / 3;
        int seg = v - row * 3;
        int n = row >> 3, i = row & 7;
        float4 val;
        if (seg == 0 && wb == 0) {
            val = make_float4(0.f, 0.f, 0.f, 0.f);   // cols -4..-1
        } else {
            int gidx = (n * Hh + (h0 + i)) * Wd + (w0 - 4 + seg * 4);
            val = *reinterpret_cast<const float4*>(x + gidx);
        }
        *reinterpret_cast<float4*>(&raw[row][seg * 4]) = val;
    }
    __syncthreads();

    const float mx      = __uint_as_float(*pmax);
    const float lsb     = exp2f(rintf(log2f(mx * 0.0078125f)) + 1.0f);  // 2^(round(log2(mx/128))+1)
    const float inv_lsb = 1.0f / lsb;

    // thread mapping: n = channel, g = 0..15 -> (row ri, col base jb), 4 pixels each
    const int n  = tid >> 4;
    const int g  = tid & 15;
    const int ri = g >> 1;
    const int jb = (g & 1) * 4;

    const float* rown = raw[n * 8 + ri];
    const float* row0 = raw[0 * 8 + ri];
    const float* row1 = raw[1 * 8 + ri];

    float xl[4], dv[4], a1v[4], a2v[4];
#pragma unroll
    for (int q = 0; q < 4; ++q) {
        int c  = 3 + jb + q;           // x_left column index in raw
        xl[q]  = rown[c];
        dv[q]  = quantv(rown[c + 1] - rown[c], inv_lsb, lsb);
        a1v[q] = quantv(row0[c + 1] - row0[c], inv_lsb, lsb);
        a2v[q] = quantv(row1[c + 1] - row1[c], inv_lsb, lsb);
    }

    // Gram sums + flat check over k=0..63 (reduce across the 16-lane group)
    float s11 = 0.f, s12 = 0.f, s22 = 0.f, s1 = 0.f, s2 = 0.f;
    float mn1 = a1v[0], mx1 = a1v[0], mn2 = a2v[0], mx2 = a2v[0];
#pragma unroll
    for (int q = 0; q < 4; ++q) {
        s11 += a1v[q] * a1v[q];
        s12 += a1v[q] * a2v[q];
        s22 += a2v[q] * a2v[q];
        s1  += a1v[q];
        s2  += a2v[q];
        mn1 = fminf(mn1, a1v[q]); mx1 = fmaxf(mx1, a1v[q]);
        mn2 = fminf(mn2, a2v[q]); mx2 = fmaxf(mx2, a2v[q]);
    }
#pragma unroll
    for (int off = 1; off < 16; off <<= 1) {
        s11 += __shfl_xor(s11, off);
        s12 += __shfl_xor(s12, off);
        s22 += __shfl_xor(s22, off);
        s1  += __shfl_xor(s1,  off);
        s2  += __shfl_xor(s2,  off);
        mn1 = fminf(mn1, __shfl_xor(mn1, off));
        mx1 = fmaxf(mx1, __shfl_xor(mx1, off));
        mn2 = fminf(mn2, __shfl_xor(mn2, off));
        mx2 = fmaxf(mx2, __shfl_xor(mx2, off));
    }
    const bool flat = ((mx1 - mn1) < 1e-6f) && ((mx2 - mn2) < 1e-6f);

    // ATA = [[s11,s12,s1],[s12,s22,s2],[s1,s2,64]]; det per JAX _det_3x3 cofactor formula
    const float a00 = s11, a01 = s12, a02 = s1;
    const float a10 = s12, a11 = s22, a12 = s2;
    const float a20 = s1,  a21 = s2,  a22 = 64.0f;
    const float det = a00 * a11 * a22 + a01 * a12 * a20 + a02 * a10 * a21
                    - a02 * a11 * a20 - a00 * a12 * a21 - a01 * a10 * a22;

    float i00, i01, i02, i11, i12, i22;
    if (det == 0.0f) {
        i00 = 1.f; i01 = 0.f; i02 = 0.f; i11 = 1.f; i12 = 0.f; i22 = 1.f;
    } else {
        const float rd = 1.0f / det;
        i00 = (a11 * a22 - a12 * a21) * rd;
        i01 = (a02 * a21 - a01 * a22) * rd;
        i02 = (a01 * a12 - a02 * a11) * rd;
        i11 = (a00 * a22 - a02 * a20) * rd;
        i12 = (a02 * a10 - a00 * a12) * rd;
        i22 = (a00 * a11 - a01 * a10) * rd;
    }

    // m = a_base @ d (per channel), reduce over 16-lane group
    float m0 = 0.f, m1 = 0.f, m2 = 0.f;
#pragma unroll
    for (int q = 0; q < 4; ++q) {
        m0 += a1v[q] * dv[q];
        m1 += a2v[q] * dv[q];
        m2 += dv[q];
    }
#pragma unroll
    for (int off = 1; off < 16; off <<= 1) {
        m0 += __shfl_xor(m0, off);
        m1 += __shfl_xor(m1, off);
        m2 += __shfl_xor(m2, off);
    }
    const float p0 = i00 * m0 + i01 * m1 + i02 * m2;
    const float p1 = i01 * m0 + i11 * m1 + i12 * m2;
    const float p2 = i02 * m0 + i12 * m1 + i22 * m2;

    // r1 = quant(a_base^T @ p); loss over 64 elements
    float r1v[4];
    float loss = 0.f;
#pragma unroll
    for (int q = 0; q < 4; ++q) {
        float r  = a1v[q] * p0 + a2v[q] * p1 + p2;
        r1v[q]   = quantv(r, inv_lsb, lsb);
        float df = dv[q] - r1v[q];
        loss += df * df;
    }
#pragma unroll
    for (int off = 1; off < 16; off <<= 1)
        loss += __shfl_xor(loss, off);

    const bool use_r = (!flat) && (loss <= 10.0f);

    float4 o;
    o.x = (use_r ? r1v[0] : dv[0]) + xl[0];
    o.y = (use_r ? r1v[1] : dv[1]) + xl[1];
    o.z = (use_r ? r1v[2] : dv[2]) + xl[2];
    o.w = (use_r ? r1v[3] : dv[3]) + xl[3];

    const int oidx = (n * Hh + (h0 + ri)) * Wd + w0 + jb;
    *reinterpret_cast<float4*>(out + oidx) = o;
}

extern "C" void kernel_launch(void* const* d_in, const int* in_sizes, int n_in,
                              void* d_out, int out_size, void* d_ws, size_t ws_size,
                              hipStream_t stream) {
    const float* x = (const float*)d_in[0];
    float* out     = (float*)d_out;
    unsigned int* pmax = (unsigned int*)d_ws;

    hipMemsetAsync(d_ws, 0, sizeof(unsigned int), stream);

    const int n4 = (NCH * Hh * Wd) / 4;   // 4M float4s
    k_maxabs<<<2048, 256, 0, stream>>>(x, pmax, n4);

    k_blocks<<<128 * 128, 256, 0, stream>>>(x, pmax, out);
}

// Round 10
// 172.274 us; speedup vs baseline: 1.1453x; 1.1453x over previous
//
#include <hip/hip_runtime.h>

static constexpr int Hh  = 1024;
static constexpr int Wd  = 1024;
static constexpr int NCH = 16;

// ---------------- Kernel 1: global max |xc| ----------------
// left neighbor via __shfl_up; only lane 0 of each wave does a scalar load.
__global__ __launch_bounds__(256) void k_maxabs(const float* __restrict__ x,
                                                unsigned int* __restrict__ omax,
                                                int n4) {
    float m = 0.0f;
    const int stride = gridDim.x * blockDim.x;
    const int lane = threadIdx.x & 63;
    for (int i = blockIdx.x * blockDim.x + threadIdx.x; i < n4; i += stride) {
        float4 v = reinterpret_cast<const float4*>(x)[i];
        float prevw = __shfl_up(v.w, 1);          // lane l-1 holds x[i*4-1]
        int w0 = (i * 4) & (Wd - 1);
        float left;
        if (w0 == 0) {
            left = 0.0f;                           // row boundary: pad
        } else if (lane == 0) {
            left = x[i * 4 - 1];                   // wave boundary: 1 scalar/wave
        } else {
            left = prevw;
        }
        float d0 = v.x - left;
        float d1 = v.y - v.x;
        float d2 = v.z - v.y;
        float d3 = v.w - v.z;
        m = fmaxf(m, fmaxf(fmaxf(fabsf(d0), fabsf(d1)), fmaxf(fabsf(d2), fabsf(d3))));
    }
#pragma unroll
    for (int off = 32; off >= 1; off >>= 1)
        m = fmaxf(m, __shfl_xor(m, off));
    __shared__ float smax[4];
    int wv = threadIdx.x >> 6;
    if (lane == 0) smax[wv] = m;
    __syncthreads();
    if (threadIdx.x == 0) {
        float mm = fmaxf(fmaxf(smax[0], smax[1]), fmaxf(smax[2], smax[3]));
        atomicMax(omax, __float_as_uint(mm));
    }
}

// ---------------- Kernel 2: per-8x8-block LS fit + select ----------------
__device__ __forceinline__ float quantv(float v, float inv_lsb, float lsb) {
    return rintf(v * inv_lsb) * lsb;   // lsb is a power of two: exact
}

// One workgroup per (hb, 64-wide strip) = 8 spatial sub-blocks.
// LDS transposed: lds[col][row] with row-dim padded to 129 floats.
//   col = 0..3   : halo (w_base-4 .. w_base-1)
//   col = 4..67  : core (w_base .. w_base+63)
//   row = ch*8+r : 128 rows
// Compute reads: fixed col, rows distinct mod 32 -> conflict-free.
// Staging writes: bank = (4j+q+row)&31, 2-way (free).
__global__ __launch_bounds__(256) void k_blocks(const float* __restrict__ x,
                                                const unsigned int* __restrict__ pmax,
                                                float* __restrict__ out) {
    // Bijective XCD-chunk swizzle: each XCD owns 16 consecutive hb rows
    // (all 16 strips) so horizontal halo neighbors share an L2.
    const int bid = blockIdx.x;            // 0..2047
    const int xcd = bid & 7;
    const int lin = xcd * 256 + (bid >> 3);
    const int hb  = lin >> 4;              // 0..127
    const int wg  = lin & 15;              // 0..15 (64-wide strip)
    const int w_base = wg * 64;
    const int h0     = hb * 8;
    const int tid = threadIdx.x;

    __shared__ float lds[68][129];

    // core: 128 rows x 16 float4 (256B per row, fully coalesced)
    for (int v = tid; v < 2048; v += 256) {
        const int row = v >> 4;            // ch*8 + r
        const int j   = v & 15;
        const int ch  = row >> 3, r = row & 7;
        const int gidx = (ch * Hh + (h0 + r)) * Wd + w_base + j * 4;
        float4 val = *reinterpret_cast<const float4*>(x + gidx);
        lds[4 + j * 4 + 0][row] = val.x;
        lds[4 + j * 4 + 1][row] = val.y;
        lds[4 + j * 4 + 2][row] = val.z;
        lds[4 + j * 4 + 3][row] = val.w;
    }
    // halo: 128 rows x 1 float4 (aligned 16B; L2-hit from same-XCD neighbor)
    if (tid < 128) {
        const int row = tid;
        const int ch = row >> 3, r = row & 7;
        float4 val;
        if (wg == 0) {
            val = make_float4(0.f, 0.f, 0.f, 0.f);
        } else {
            const int gidx = (ch * Hh + (h0 + r)) * Wd + w_base - 4;
            val = *reinterpret_cast<const float4*>(x + gidx);
        }
        lds[0][row] = val.x;
        lds[1][row] = val.y;
        lds[2][row] = val.z;
        lds[3][row] = val.w;
    }
    __syncthreads();

    const float mx      = __uint_as_float(*pmax);
    const float lsb     = exp2f(rintf(log2f(mx * 0.0078125f)) + 1.0f);  // 2^(round(log2(mx/128))+1)
    const float inv_lsb = 1.0f / lsb;

    // thread mapping: ch = tid>>4; g = tid&15 -> (row ri, col half jb)
    const int ch = tid >> 4;
    const int g  = tid & 15;
    const int ri = g >> 1;
    const int jb = (g & 1) * 4;

    const int rowN = ch * 8 + ri;
    const int r0   = ri;          // channel 0 rows
    const int r1   = 8 + ri;      // channel 1 rows

    for (int sb = 0; sb < 8; ++sb) {
        const int cb = 4 + sb * 8 + jb;    // lds column of first output pixel

        float xl[4], dvv[4], a1v[4], a2v[4];
#pragma unroll
        for (int q = 0; q < 4; ++q) {
            const int c = cb + q;
            xl[q]  = lds[c - 1][rowN];
            dvv[q] = quantv(lds[c][rowN] - xl[q], inv_lsb, lsb);
            a1v[q] = quantv(lds[c][r0] - lds[c - 1][r0], inv_lsb, lsb);
            a2v[q] = quantv(lds[c][r1] - lds[c - 1][r1], inv_lsb, lsb);
        }

        // Gram sums + flat check over the 64-px block (16-lane group reduce)
        float s11 = 0.f, s12 = 0.f, s22 = 0.f, s1 = 0.f, s2 = 0.f;
        float mn1 = a1v[0], mx1 = a1v[0], mn2 = a2v[0], mx2 = a2v[0];
#pragma unroll
        for (int q = 0; q < 4; ++q) {
            s11 += a1v[q] * a1v[q];
            s12 += a1v[q] * a2v[q];
            s22 += a2v[q] * a2v[q];
            s1  += a1v[q];
            s2  += a2v[q];
            mn1 = fminf(mn1, a1v[q]); mx1 = fmaxf(mx1, a1v[q]);
            mn2 = fminf(mn2, a2v[q]); mx2 = fmaxf(mx2, a2v[q]);
        }
#pragma unroll
        for (int off = 1; off < 16; off <<= 1) {
            s11 += __shfl_xor(s11, off);
            s12 += __shfl_xor(s12, off);
            s22 += __shfl_xor(s22, off);
            s1  += __shfl_xor(s1,  off);
            s2  += __shfl_xor(s2,  off);
            mn1 = fminf(mn1, __shfl_xor(mn1, off));
            mx1 = fmaxf(mx1, __shfl_xor(mx1, off));
            mn2 = fminf(mn2, __shfl_xor(mn2, off));
            mx2 = fmaxf(mx2, __shfl_xor(mx2, off));
        }
        const bool flat = ((mx1 - mn1) < 1e-6f) && ((mx2 - mn2) < 1e-6f);

        // ATA and det (cofactor expansion, matches JAX det_3x3)
        const float a00 = s11, a01 = s12, a02 = s1;
        const float a10 = s12, a11 = s22, a12 = s2;
        const float a20 = s1,  a21 = s2,  a22 = 64.0f;
        const float det = a00 * a11 * a22 + a01 * a12 * a20 + a02 * a10 * a21
                        - a02 * a11 * a20 - a00 * a12 * a21 - a01 * a10 * a22;

        float i00, i01, i02, i11, i12, i22;
        if (det == 0.0f) {
            i00 = 1.f; i01 = 0.f; i02 = 0.f; i11 = 1.f; i12 = 0.f; i22 = 1.f;
        } else {
            const float rd = 1.0f / det;
            i00 = (a11 * a22 - a12 * a21) * rd;
            i01 = (a02 * a21 - a01 * a22) * rd;
            i02 = (a01 * a12 - a02 * a11) * rd;
            i11 = (a00 * a22 - a02 * a20) * rd;
            i12 = (a02 * a10 - a00 * a12) * rd;
            i22 = (a00 * a11 - a01 * a10) * rd;
        }

        // m = a_base @ d (per channel)
        float m0 = 0.f, m1 = 0.f, m2 = 0.f;
#pragma unroll
        for (int q = 0; q < 4; ++q) {
            m0 += a1v[q] * dvv[q];
            m1 += a2v[q] * dvv[q];
            m2 += dvv[q];
        }
#pragma unroll
        for (int off = 1; off < 16; off <<= 1) {
            m0 += __shfl_xor(m0, off);
            m1 += __shfl_xor(m1, off);
            m2 += __shfl_xor(m2, off);
        }
        const float p0 = i00 * m0 + i01 * m1 + i02 * m2;
        const float p1 = i01 * m0 + i11 * m1 + i12 * m2;
        const float p2 = i02 * m0 + i12 * m1 + i22 * m2;

        // r1 = quant(a_base^T @ p); loss over 64 px
        float r1v[4];
        float loss = 0.f;
#pragma unroll
        for (int q = 0; q < 4; ++q) {
            float r  = a1v[q] * p0 + a2v[q] * p1 + p2;
            r1v[q]   = quantv(r, inv_lsb, lsb);
            float df = dvv[q] - r1v[q];
            loss += df * df;
        }
#pragma unroll
        for (int off = 1; off < 16; off <<= 1)
            loss += __shfl_xor(loss, off);

        const bool use_r = (!flat) && (loss <= 10.0f);

        float4 o;
        o.x = (use_r ? r1v[0] : dvv[0]) + xl[0];
        o.y = (use_r ? r1v[1] : dvv[1]) + xl[1];
        o.z = (use_r ? r1v[2] : dvv[2]) + xl[2];
        o.w = (use_r ? r1v[3] : dvv[3]) + xl[3];

        const int oidx = (ch * Hh + (h0 + ri)) * Wd + w_base + sb * 8 + jb;
        *reinterpret_cast<float4*>(out + oidx) = o;
    }
}

extern "C" void kernel_launch(void* const* d_in, const int* in_sizes, int n_in,
                              void* d_out, int out_size, void* d_ws, size_t ws_size,
                              hipStream_t stream) {
    const float* x = (const float*)d_in[0];
    float* out     = (float*)d_out;
    unsigned int* pmax = (unsigned int*)d_ws;

    hipMemsetAsync(d_ws, 0, sizeof(unsigned int), stream);

    const int n4 = (NCH * Hh * Wd) / 4;   // 4M float4s
    k_maxabs<<<2048, 256, 0, stream>>>(x, pmax, n4);

    k_blocks<<<128 * 16, 256, 0, stream>>>(x, pmax, out);
}